// Round 7
// baseline (490.172 us; speedup 1.0000x reference)
//
#include <hip/hip_runtime.h>

#define NCLS 16
#define NB 391      // ceil(100000/256) buckets of 256 node IDs
#define BSH 8       // bucket = dst >> 8, local node = dst & 255
#define TILE 4096
#define PREB 512    // blocks devoted to bhist inside pre_kernel
#define SUMSTRIDE 17  // LDS row pad: breaks (node*16)%32 ∈ {0,16} bank degeneracy
#define DSTRIDE 20    // LDS dvec row stride (float4-aligned, non-pow2)

static __device__ __forceinline__ float bflo(unsigned u) {
  return __uint_as_float(u << 16);
}
static __device__ __forceinline__ float bfhi(unsigned u) {
  return __uint_as_float(u & 0xFFFF0000u);
}
static __device__ __forceinline__ unsigned f2bf1(float f) {
  unsigned u = __float_as_uint(f);
  return (u + 0x7FFF + ((u >> 16) & 1)) >> 16;  // RNE
}
static __device__ __forceinline__ unsigned packbf(float a, float b) {
  return f2bf1(a) | (f2bf1(b) << 16);
}

// ---- fused: bucket histogram (blocks 0..PREB-1) + f32->bf16 convert (rest) ----
__global__ void pre_kernel(const int* __restrict__ dstv, int* __restrict__ bcnt, int E,
                           const float2* __restrict__ aug, unsigned* __restrict__ augh, int n2) {
  __shared__ int lh[NB];
  if (blockIdx.x < PREB) {
    for (int t = threadIdx.x; t < NB; t += 256) lh[t] = 0;
    __syncthreads();
    int stride = PREB * 256;
    for (int i = blockIdx.x * 256 + threadIdx.x; i < E; i += stride)
      atomicAdd(&lh[dstv[i] >> BSH], 1);
    __syncthreads();
    for (int t = threadIdx.x; t < NB; t += 256) {
      int v = lh[t];
      if (v) atomicAdd(&bcnt[t], v);
    }
  } else {
    int i = (blockIdx.x - PREB) * 256 + threadIdx.x;
    if (i < n2) {
      float2 v = aug[i];
      augh[i] = packbf(v.x, v.y);
    }
  }
}

// ---- exclusive scan of 391 bucket counts (single block, 512 thr) ----
__global__ void bscan_kernel(const int* __restrict__ bcnt, int* __restrict__ bbase,
                             int* __restrict__ gcur) {
  __shared__ int tmp[512];
  int t = threadIdx.x;
  int x = (t < NB) ? bcnt[t] : 0;
  tmp[t] = x;
  __syncthreads();
  for (int o = 1; o < 512; o <<= 1) {
    int v = (t >= o) ? tmp[t - o] : 0;
    __syncthreads();
    tmp[t] += v;
    __syncthreads();
  }
  if (t < NB) { int e = tmp[t] - x; bbase[t] = e; gcur[t] = e; }
  if (t == NB - 1) bbase[NB] = tmp[t];
}

// ---- bin pass: tile-local bucket sort in LDS; stage {val, gdest}; coalesced flush ----
__global__ void __launch_bounds__(256) bin_kernel(const int* __restrict__ srcv,
                                                  const int* __restrict__ dstv,
                                                  int* __restrict__ gcur,
                                                  int* __restrict__ packed, int E) {
  __shared__ int hist[NB];
  __shared__ int off[NB];
  __shared__ int delta[NB];   // gb[b] - off[b]
  __shared__ int cur[NB];
  __shared__ int part[16];
  __shared__ int2 stag[TILE];
  int tid = threadIdx.x;
  int base = blockIdx.x * TILE;
  int cnt = min(TILE, E - base);
  for (int t = tid; t < NB; t += 256) hist[t] = 0;
  __syncthreads();
  for (int k = tid; k < cnt; k += 256)
    atomicAdd(&hist[dstv[base + k] >> BSH], 1);
  __syncthreads();
  // two-level exclusive scan of hist
  if (tid < 16) {
    int s = 0;
    int lo = tid * 25, hiX = min(NB, lo + 25);
    for (int j = lo; j < hiX; j++) { int v = hist[j]; off[j] = s; s += v; }
    part[tid] = s;
  }
  __syncthreads();
  if (tid == 0) {
    int run = 0;
    for (int j = 0; j < 16; j++) { int v = part[j]; part[j] = run; run += v; }
  }
  __syncthreads();
  for (int t = tid; t < NB; t += 256) off[t] += part[t / 25];
  __syncthreads();
  for (int t = tid; t < NB; t += 256) {
    int c = hist[t];
    int gb = c ? atomicAdd(&gcur[t], c) : 0;
    delta[t] = gb - off[t];
    cur[t] = off[t];
  }
  __syncthreads();
  for (int k = tid; k < cnt; k += 256) {
    int s = srcv[base + k], d = dstv[base + k];
    int b = d >> BSH;
    int p = atomicAdd(&cur[b], 1);
    int2 w;
    w.x = s | ((d & 255) << 17);
    w.y = p + delta[b];
    stag[p] = w;
  }
  __syncthreads();
  for (int i = tid; i < cnt; i += 256) {
    int2 w = stag[i];
    packed[w.y] = w.x;
  }
}

// ---- pass A: per-bucket aggregation via LDS atomics + node math ----
// One 512-thread block per bucket. 2 lanes/edge (uint4 = 8 bf16 each), unroll-2.
__global__ void __launch_bounds__(512) agg_node_kernel(
    const int* __restrict__ bbase, const int* __restrict__ packed,
    const unsigned* __restrict__ augh, unsigned* __restrict__ logs,
    float* __restrict__ dvec, double* __restrict__ acc, int N) {
  __shared__ float sums[256 * SUMSTRIDE];
  __shared__ int ldeg[256];
  __shared__ float red[8];
  int tid = threadIdx.x;
  int b = blockIdx.x;
  int beg = bbase[b], end = bbase[b + 1];
  int nb0 = b << BSH;
  for (int i = tid; i < 256 * SUMSTRIDE; i += 512) sums[i] = 0.f;
  if (tid < 256) ldeg[tid] = 0;
  __syncthreads();
  int t = tid & 1;
  int woff = t << 2;
  int e = beg + (tid >> 1);
  for (; e + 256 < end; e += 512) {
    int w1 = packed[e], w2 = packed[e + 256];
    uint4 v1 = *reinterpret_cast<const uint4*>(augh + ((size_t)(w1 & 0x1FFFF) << 3) + woff);
    uint4 v2 = *reinterpret_cast<const uint4*>(augh + ((size_t)(w2 & 0x1FFFF) << 3) + woff);
    float* r1 = sums + ((w1 >> 17) & 255) * SUMSTRIDE + (t << 3);
    float* r2 = sums + ((w2 >> 17) & 255) * SUMSTRIDE + (t << 3);
    atomicAdd(r1 + 0, bflo(v1.x)); atomicAdd(r1 + 1, bfhi(v1.x));
    atomicAdd(r1 + 2, bflo(v1.y)); atomicAdd(r1 + 3, bfhi(v1.y));
    atomicAdd(r1 + 4, bflo(v1.z)); atomicAdd(r1 + 5, bfhi(v1.z));
    atomicAdd(r1 + 6, bflo(v1.w)); atomicAdd(r1 + 7, bfhi(v1.w));
    atomicAdd(r2 + 0, bflo(v2.x)); atomicAdd(r2 + 1, bfhi(v2.x));
    atomicAdd(r2 + 2, bflo(v2.y)); atomicAdd(r2 + 3, bfhi(v2.y));
    atomicAdd(r2 + 4, bflo(v2.z)); atomicAdd(r2 + 5, bfhi(v2.z));
    atomicAdd(r2 + 6, bflo(v2.w)); atomicAdd(r2 + 7, bfhi(v2.w));
    if (t == 0) {
      atomicAdd(&ldeg[(w1 >> 17) & 255], 1);
      atomicAdd(&ldeg[(w2 >> 17) & 255], 1);
    }
  }
  if (e < end) {
    int w1 = packed[e];
    uint4 v1 = *reinterpret_cast<const uint4*>(augh + ((size_t)(w1 & 0x1FFFF) << 3) + woff);
    float* r1 = sums + ((w1 >> 17) & 255) * SUMSTRIDE + (t << 3);
    atomicAdd(r1 + 0, bflo(v1.x)); atomicAdd(r1 + 1, bfhi(v1.x));
    atomicAdd(r1 + 2, bflo(v1.y)); atomicAdd(r1 + 3, bfhi(v1.y));
    atomicAdd(r1 + 4, bflo(v1.z)); atomicAdd(r1 + 5, bfhi(v1.z));
    atomicAdd(r1 + 6, bflo(v1.w)); atomicAdd(r1 + 7, bfhi(v1.w));
    if (t == 0) atomicAdd(&ldeg[(w1 >> 17) & 255], 1);
  }
  __syncthreads();
  float contrib = 0.f;
  if (tid < 256) {
    int g = nb0 + tid;
    if (g < N) {
      int deg = ldeg[tid];
      float inv = 1.0f / fmaxf((float)deg, 1.0f);
      float a[NCLS];
      float psum = 0.f;
      const float* srow = sums + tid * SUMSTRIDE;
#pragma unroll
      for (int k = 0; k < NCLS; k++) {
        float v = srow[k] * inv;
        a[k] = v;
        psum += v * v;
      }
      float ip = 1.0f / psum;
      float h = 0.f;
      float dd[NCLS];
#pragma unroll
      for (int k = 0; k < NCLS; k++) {
        float d = a[k] * a[k] * ip + 1e-10f;
        dd[k] = d;
        h += d * __logf(d);
      }
      uint4 lw0, lw1;
      lw0.x = packbf(__logf(a[0] + 1e-10f), __logf(a[1] + 1e-10f));
      lw0.y = packbf(__logf(a[2] + 1e-10f), __logf(a[3] + 1e-10f));
      lw0.z = packbf(__logf(a[4] + 1e-10f), __logf(a[5] + 1e-10f));
      lw0.w = packbf(__logf(a[6] + 1e-10f), __logf(a[7] + 1e-10f));
      lw1.x = packbf(__logf(a[8] + 1e-10f), __logf(a[9] + 1e-10f));
      lw1.y = packbf(__logf(a[10] + 1e-10f), __logf(a[11] + 1e-10f));
      lw1.z = packbf(__logf(a[12] + 1e-10f), __logf(a[13] + 1e-10f));
      lw1.w = packbf(__logf(a[14] + 1e-10f), __logf(a[15] + 1e-10f));
      uint4* lbase = reinterpret_cast<uint4*>(logs + ((size_t)g << 3));
      lbase[0] = lw0;
      lbase[1] = lw1;
      float4* dbase = reinterpret_cast<float4*>(dvec + ((size_t)g << 4));
#pragma unroll
      for (int q = 0; q < 4; q++) {
        float4 dv;
        dv.x = dd[q * 4]; dv.y = dd[q * 4 + 1]; dv.z = dd[q * 4 + 2]; dv.w = dd[q * 4 + 3];
        dbase[q] = dv;
      }
      contrib = (float)deg * h;
    }
  }
#pragma unroll
  for (int o = 32; o >= 1; o >>= 1) contrib += __shfl_xor(contrib, o, 64);
  int wave = tid >> 6;
  if ((tid & 63) == 0) red[wave] = contrib;
  __syncthreads();
  if (tid == 0) {
    float s = 0.f;
#pragma unroll
    for (int j = 0; j < 8; j++) s += red[j];
    atomicAdd(acc, (double)s);
  }
}

// ---- pass B: per-bucket loss; dvec in LDS, gather logs[src] ----
__global__ void __launch_bounds__(512) loss_kernel(
    const int* __restrict__ bbase, const int* __restrict__ packed,
    const unsigned* __restrict__ logs, const float* __restrict__ dvec,
    double* __restrict__ acc, int N) {
  __shared__ float ldv[256 * DSTRIDE];
  __shared__ float red[8];
  int tid = threadIdx.x;
  int b = blockIdx.x;
  int beg = bbase[b], end = bbase[b + 1];
  int nb0 = b << BSH;
  {
    int local = tid >> 1, tt = tid & 1;
    int g = nb0 + local;
    if (g < N) {
      const float* sp = dvec + ((size_t)g << 4) + (tt << 3);
      float4 d0 = *reinterpret_cast<const float4*>(sp);
      float4 d1 = *reinterpret_cast<const float4*>(sp + 4);
      float* dp = ldv + local * DSTRIDE + (tt << 3);
      *reinterpret_cast<float4*>(dp) = d0;
      *reinterpret_cast<float4*>(dp + 4) = d1;
    }
  }
  __syncthreads();
  float dot = 0.f;
  int t = tid & 1;
  int woff = t << 2;
  int e = beg + (tid >> 1);
  for (; e + 256 < end; e += 512) {
    int w1 = packed[e], w2 = packed[e + 256];
    uint4 v1 = *reinterpret_cast<const uint4*>(logs + ((size_t)(w1 & 0x1FFFF) << 3) + woff);
    uint4 v2 = *reinterpret_cast<const uint4*>(logs + ((size_t)(w2 & 0x1FFFF) << 3) + woff);
    const float* r1 = ldv + ((w1 >> 17) & 255) * DSTRIDE + (t << 3);
    const float* r2 = ldv + ((w2 >> 17) & 255) * DSTRIDE + (t << 3);
    float4 da0 = *reinterpret_cast<const float4*>(r1);
    float4 da1 = *reinterpret_cast<const float4*>(r1 + 4);
    float4 db0 = *reinterpret_cast<const float4*>(r2);
    float4 db1 = *reinterpret_cast<const float4*>(r2 + 4);
    dot += da0.x * bflo(v1.x) + da0.y * bfhi(v1.x) + da0.z * bflo(v1.y) + da0.w * bfhi(v1.y) +
           da1.x * bflo(v1.z) + da1.y * bfhi(v1.z) + da1.z * bflo(v1.w) + da1.w * bfhi(v1.w);
    dot += db0.x * bflo(v2.x) + db0.y * bfhi(v2.x) + db0.z * bflo(v2.y) + db0.w * bfhi(v2.y) +
           db1.x * bflo(v2.z) + db1.y * bfhi(v2.z) + db1.z * bflo(v2.w) + db1.w * bfhi(v2.w);
  }
  if (e < end) {
    int w1 = packed[e];
    uint4 v1 = *reinterpret_cast<const uint4*>(logs + ((size_t)(w1 & 0x1FFFF) << 3) + woff);
    const float* r1 = ldv + ((w1 >> 17) & 255) * DSTRIDE + (t << 3);
    float4 da0 = *reinterpret_cast<const float4*>(r1);
    float4 da1 = *reinterpret_cast<const float4*>(r1 + 4);
    dot += da0.x * bflo(v1.x) + da0.y * bfhi(v1.x) + da0.z * bflo(v1.y) + da0.w * bfhi(v1.y) +
           da1.x * bflo(v1.z) + da1.y * bfhi(v1.z) + da1.z * bflo(v1.w) + da1.w * bfhi(v1.w);
  }
#pragma unroll
  for (int o = 32; o >= 1; o >>= 1) dot += __shfl_xor(dot, o, 64);
  int wave = tid >> 6;
  if ((tid & 63) == 0) red[wave] = dot;
  __syncthreads();
  if (tid == 0) {
    float s = 0.f;
#pragma unroll
    for (int j = 0; j < 8; j++) s += red[j];
    atomicAdd(acc, -(double)s);
  }
}

__global__ void finalize_kernel(const double* __restrict__ acc,
                                float* __restrict__ out, int E) {
  if (threadIdx.x == 0 && blockIdx.x == 0)
    out[0] = (float)(acc[0] / (double)E);
}

extern "C" void kernel_launch(void* const* d_in, const int* in_sizes, int n_in,
                              void* d_out, int out_size, void* d_ws, size_t ws_size,
                              hipStream_t stream) {
  const int* edge_index = (const int*)d_in[0];
  const float* aug_pred = (const float*)d_in[1];
  const int E = in_sizes[0] / 2;
  const int N = in_sizes[1] / NCLS;

  const int* srcv = edge_index;
  const int* dstv = edge_index + E;

  // 256B-aligned bump allocator over d_ws
  char* p = (char*)d_ws;
  auto alloc = [&](size_t bytes) {
    char* r = p;
    p += (bytes + 255) & ~(size_t)255;
    return r;
  };
  double* acc = (double*)alloc(8);
  int* bcnt = (int*)alloc(NB * 4);
  int* bbase = (int*)alloc((NB + 1) * 4);
  int* gcur = (int*)alloc(NB * 4);
  int* packed = (int*)alloc((size_t)E * 4);
  unsigned* augh = (unsigned*)alloc((size_t)N * NCLS * 2);
  unsigned* logs = (unsigned*)alloc((size_t)N * NCLS * 2);
  float* dvec = (float*)alloc((size_t)N * NCLS * 4);

  // zero acc + bcnt (contiguous prefix of the arena)
  size_t zero_bytes = (size_t)((char*)bbase - (char*)d_ws);
  hipMemsetAsync(d_ws, 0, zero_bytes, stream);

  int n2 = N * NCLS / 2;
  int cvtb = (n2 + 255) / 256;
  pre_kernel<<<PREB + cvtb, 256, 0, stream>>>(dstv, bcnt, E, (const float2*)aug_pred, augh, n2);
  bscan_kernel<<<1, 512, 0, stream>>>(bcnt, bbase, gcur);
  int tiles = (E + TILE - 1) / TILE;
  bin_kernel<<<tiles, 256, 0, stream>>>(srcv, dstv, gcur, packed, E);
  agg_node_kernel<<<NB, 512, 0, stream>>>(bbase, packed, augh, logs, dvec, acc, N);
  loss_kernel<<<NB, 512, 0, stream>>>(bbase, packed, logs, dvec, acc, N);
  finalize_kernel<<<1, 64, 0, stream>>>(acc, (float*)d_out, E);
}

// Round 9
// 226.757 us; speedup vs baseline: 2.1617x; 2.1617x over previous
//
#include <hip/hip_runtime.h>

#define NCLS 16
#define NB 391      // ceil(100000/256) buckets of 256 node IDs
#define BSH 8       // bucket = dst >> 8, local node = dst & 255
#define TILE 4096
#define CAP 18      // per-thread capacity in csr_sort (18*512=9216 > max bucket ~8600)
#define PREB 512    // blocks devoted to bhist inside pre_kernel

static __device__ __forceinline__ float bflo(unsigned u) {
  return __uint_as_float(u << 16);
}
static __device__ __forceinline__ float bfhi(unsigned u) {
  return __uint_as_float(u & 0xFFFF0000u);
}
static __device__ __forceinline__ unsigned f2bf1(float f) {
  unsigned u = __float_as_uint(f);
  return (u + 0x7FFF + ((u >> 16) & 1)) >> 16;  // RNE
}
static __device__ __forceinline__ unsigned packbf(float a, float b) {
  return f2bf1(a) | (f2bf1(b) << 16);
}

// ---- fused: bucket histogram (blocks 0..PREB-1) + f32->bf16 convert (rest) ----
__global__ void pre_kernel(const int* __restrict__ dstv, int* __restrict__ bcnt, int E,
                           const float2* __restrict__ aug, unsigned* __restrict__ augh, int n2) {
  __shared__ int lh[NB];
  if (blockIdx.x < PREB) {
    for (int t = threadIdx.x; t < NB; t += 256) lh[t] = 0;
    __syncthreads();
    int stride = PREB * 256;
    for (int i = blockIdx.x * 256 + threadIdx.x; i < E; i += stride)
      atomicAdd(&lh[dstv[i] >> BSH], 1);
    __syncthreads();
    for (int t = threadIdx.x; t < NB; t += 256) {
      int v = lh[t];
      if (v) atomicAdd(&bcnt[t], v);
    }
  } else {
    int i = (blockIdx.x - PREB) * 256 + threadIdx.x;
    if (i < n2) {
      float2 v = aug[i];
      augh[i] = packbf(v.x, v.y);
    }
  }
}

// ---- exclusive scan of 391 bucket counts (single block, 512 thr) ----
__global__ void bscan_kernel(const int* __restrict__ bcnt, int* __restrict__ bbase,
                             int* __restrict__ gcur, int* __restrict__ offsets,
                             int N, int E) {
  __shared__ int tmp[512];
  int t = threadIdx.x;
  int x = (t < NB) ? bcnt[t] : 0;
  tmp[t] = x;
  __syncthreads();
  for (int o = 1; o < 512; o <<= 1) {
    int v = (t >= o) ? tmp[t - o] : 0;
    __syncthreads();
    tmp[t] += v;
    __syncthreads();
  }
  if (t < NB) { int e = tmp[t] - x; bbase[t] = e; gcur[t] = e; }
  if (t == NB - 1) bbase[NB] = tmp[t];
  if (t == 0) offsets[N] = E;   // sentinel for the last node's CSR range
}

// ---- bin pass: tile-local bucket sort in LDS; stage {val, gdest}; coalesced flush ----
// 512 threads: 40KB LDS -> 4 blocks/CU, 32 waves = full occupancy ceiling.
__global__ void __launch_bounds__(512) bin_kernel(const int* __restrict__ srcv,
                                                  const int* __restrict__ dstv,
                                                  int* __restrict__ gcur,
                                                  int* __restrict__ packed, int E) {
  __shared__ int hist[NB];
  __shared__ int off[NB];
  __shared__ int delta[NB];   // gb[b] - off[b]
  __shared__ int cur[NB];
  __shared__ int part[16];
  __shared__ int2 stag[TILE];
  int tid = threadIdx.x;
  int base = blockIdx.x * TILE;
  int cnt = min(TILE, E - base);
  for (int t = tid; t < NB; t += 512) hist[t] = 0;
  __syncthreads();
  for (int k = tid; k < cnt; k += 512)
    atomicAdd(&hist[dstv[base + k] >> BSH], 1);
  __syncthreads();
  // two-level exclusive scan of hist
  if (tid < 16) {
    int s = 0;
    int lo = tid * 25, hiX = min(NB, lo + 25);
    for (int j = lo; j < hiX; j++) { int v = hist[j]; off[j] = s; s += v; }
    part[tid] = s;
  }
  __syncthreads();
  if (tid == 0) {
    int run = 0;
    for (int j = 0; j < 16; j++) { int v = part[j]; part[j] = run; run += v; }
  }
  __syncthreads();
  for (int t = tid; t < NB; t += 512) off[t] += part[t / 25];
  __syncthreads();
  for (int t = tid; t < NB; t += 512) {
    int c = hist[t];
    int gb = c ? atomicAdd(&gcur[t], c) : 0;
    delta[t] = gb - off[t];
    cur[t] = off[t];
  }
  __syncthreads();
  for (int k = tid; k < cnt; k += 512) {
    int s = srcv[base + k], d = dstv[base + k];
    int b = d >> BSH;
    int p = atomicAdd(&cur[b], 1);
    int2 w;
    w.x = s | ((d & 255) << 17);
    w.y = p + delta[b];
    stag[p] = w;
  }
  __syncthreads();
  for (int i = tid; i < cnt; i += 512) {
    int2 w = stag[i];
    packed[w.y] = w.x;
  }
}

// ---- per-bucket CSR finalize: node offsets + in-place sort of src ----
// 512 threads, CAP=18: shallower serial loops, 8 waves/block for latency hiding.
__global__ void __launch_bounds__(512) csr_sort_kernel(const int* __restrict__ bbase,
                                                        int* __restrict__ packed,
                                                        int* __restrict__ offsets, int N) {
  __shared__ int cnt[256];
  __shared__ int off[256];
  __shared__ int cur[256];
  int tid = threadIdx.x;
  int b = blockIdx.x;
  int rbeg = bbase[b], rend = bbase[b + 1];
  int nb0 = b << BSH;
  int myv[CAP];
#pragma unroll
  for (int k = 0; k < CAP; k++) {
    int i = rbeg + tid + k * 512;
    myv[k] = (i < rend) ? packed[i] : -1;
  }
  if (tid < 256) cnt[tid] = 0;
  __syncthreads();
#pragma unroll
  for (int k = 0; k < CAP; k++)
    if (myv[k] >= 0) atomicAdd(&cnt[myv[k] >> 17], 1);
  __syncthreads();
  int x = 0;
  if (tid < 256) {
    x = cnt[tid];
    off[tid] = x;
  }
  __syncthreads();
  for (int o = 1; o < 256; o <<= 1) {
    int v = (tid < 256 && tid >= o) ? off[tid - o] : 0;
    __syncthreads();
    if (tid < 256) off[tid] += v;
    __syncthreads();
  }
  if (tid < 256) {
    int excl = off[tid] - x;
    cur[tid] = excl;
    int g = nb0 + tid;
    if (g < N) offsets[g] = rbeg + excl;
  }
  __syncthreads();
#pragma unroll
  for (int k = 0; k < CAP; k++) {
    int w = myv[k];
    if (w >= 0) {
      int ln = w >> 17;
      int p = atomicAdd(&cur[ln], 1);
      packed[rbeg + p] = w & 0x1FFFF;
    }
  }
}

// ---- pull 1: scatter-mean + node math; 2 lanes/node, uint4 gathers, unroll-8 ----
__global__ void pull_node_kernel(const int* __restrict__ offsets,
                                 const int* __restrict__ sorted_src,
                                 const unsigned* __restrict__ augh,  // bf16x2 words [N*8]
                                 unsigned* __restrict__ logs,        // bf16x2 words [N*8]
                                 float* __restrict__ dvec,           // f32 [N*16]
                                 double* __restrict__ acc, int N) {
  int gid = blockIdx.x * blockDim.x + threadIdx.x;
  int g = gid >> 1;
  int t = gid & 1;
  float contrib = 0.f;
  if (g < N) {
    int beg = offsets[g], end = offsets[g + 1];
    int deg = end - beg;
    float s0 = 0.f, s1 = 0.f, s2 = 0.f, s3 = 0.f, s4 = 0.f, s5 = 0.f, s6 = 0.f, s7 = 0.f;
    int woff = t << 2;  // word offset within row (4 uints = 8 bf16)
    int i = beg;
    for (; i + 8 <= end; i += 8) {
      int i0 = sorted_src[i],     i1 = sorted_src[i + 1];
      int i2 = sorted_src[i + 2], i3 = sorted_src[i + 3];
      int i4 = sorted_src[i + 4], i5 = sorted_src[i + 5];
      int i6 = sorted_src[i + 6], i7 = sorted_src[i + 7];
      uint4 w0 = *reinterpret_cast<const uint4*>(augh + ((size_t)i0 << 3) + woff);
      uint4 w1 = *reinterpret_cast<const uint4*>(augh + ((size_t)i1 << 3) + woff);
      uint4 w2 = *reinterpret_cast<const uint4*>(augh + ((size_t)i2 << 3) + woff);
      uint4 w3 = *reinterpret_cast<const uint4*>(augh + ((size_t)i3 << 3) + woff);
      uint4 w4 = *reinterpret_cast<const uint4*>(augh + ((size_t)i4 << 3) + woff);
      uint4 w5 = *reinterpret_cast<const uint4*>(augh + ((size_t)i5 << 3) + woff);
      uint4 w6 = *reinterpret_cast<const uint4*>(augh + ((size_t)i6 << 3) + woff);
      uint4 w7 = *reinterpret_cast<const uint4*>(augh + ((size_t)i7 << 3) + woff);
      s0 += bflo(w0.x) + bflo(w1.x) + bflo(w2.x) + bflo(w3.x) + bflo(w4.x) + bflo(w5.x) + bflo(w6.x) + bflo(w7.x);
      s1 += bfhi(w0.x) + bfhi(w1.x) + bfhi(w2.x) + bfhi(w3.x) + bfhi(w4.x) + bfhi(w5.x) + bfhi(w6.x) + bfhi(w7.x);
      s2 += bflo(w0.y) + bflo(w1.y) + bflo(w2.y) + bflo(w3.y) + bflo(w4.y) + bflo(w5.y) + bflo(w6.y) + bflo(w7.y);
      s3 += bfhi(w0.y) + bfhi(w1.y) + bfhi(w2.y) + bfhi(w3.y) + bfhi(w4.y) + bfhi(w5.y) + bfhi(w6.y) + bfhi(w7.y);
      s4 += bflo(w0.z) + bflo(w1.z) + bflo(w2.z) + bflo(w3.z) + bflo(w4.z) + bflo(w5.z) + bflo(w6.z) + bflo(w7.z);
      s5 += bfhi(w0.z) + bfhi(w1.z) + bfhi(w2.z) + bfhi(w3.z) + bfhi(w4.z) + bfhi(w5.z) + bfhi(w6.z) + bfhi(w7.z);
      s6 += bflo(w0.w) + bflo(w1.w) + bflo(w2.w) + bflo(w3.w) + bflo(w4.w) + bflo(w5.w) + bflo(w6.w) + bflo(w7.w);
      s7 += bfhi(w0.w) + bfhi(w1.w) + bfhi(w2.w) + bfhi(w3.w) + bfhi(w4.w) + bfhi(w5.w) + bfhi(w6.w) + bfhi(w7.w);
    }
    for (; i < end; i++) {
      int i0 = sorted_src[i];
      uint4 w0 = *reinterpret_cast<const uint4*>(augh + ((size_t)i0 << 3) + woff);
      s0 += bflo(w0.x); s1 += bfhi(w0.x);
      s2 += bflo(w0.y); s3 += bfhi(w0.y);
      s4 += bflo(w0.z); s5 += bfhi(w0.z);
      s6 += bflo(w0.w); s7 += bfhi(w0.w);
    }
    float c = fmaxf((float)deg, 1.0f);
    float inv = 1.0f / c;
    float a0 = s0 * inv, a1 = s1 * inv, a2 = s2 * inv, a3 = s3 * inv;
    float a4 = s4 * inv, a5 = s5 * inv, a6 = s6 * inv, a7 = s7 * inv;
    float p2 = a0 * a0 + a1 * a1 + a2 * a2 + a3 * a3 + a4 * a4 + a5 * a5 + a6 * a6 + a7 * a7;
    float psum = p2 + __shfl_xor(p2, 1, 64);
    float ip = 1.0f / psum;
    float d0 = a0 * a0 * ip + 1e-10f, d1 = a1 * a1 * ip + 1e-10f;
    float d2 = a2 * a2 * ip + 1e-10f, d3 = a3 * a3 * ip + 1e-10f;
    float d4 = a4 * a4 * ip + 1e-10f, d5 = a5 * a5 * ip + 1e-10f;
    float d6 = a6 * a6 * ip + 1e-10f, d7 = a7 * a7 * ip + 1e-10f;
    uint4 lw;
    lw.x = packbf(__logf(a0 + 1e-10f), __logf(a1 + 1e-10f));
    lw.y = packbf(__logf(a2 + 1e-10f), __logf(a3 + 1e-10f));
    lw.z = packbf(__logf(a4 + 1e-10f), __logf(a5 + 1e-10f));
    lw.w = packbf(__logf(a6 + 1e-10f), __logf(a7 + 1e-10f));
    *reinterpret_cast<uint4*>(logs + ((size_t)g << 3) + woff) = lw;
    float4 dd0, dd1;
    dd0.x = d0; dd0.y = d1; dd0.z = d2; dd0.w = d3;
    dd1.x = d4; dd1.y = d5; dd1.z = d6; dd1.w = d7;
    float* dbase = dvec + ((size_t)g << 4) + (t << 3);
    *reinterpret_cast<float4*>(dbase) = dd0;
    *reinterpret_cast<float4*>(dbase + 4) = dd1;
    float h = d0 * __logf(d0) + d1 * __logf(d1) + d2 * __logf(d2) + d3 * __logf(d3) +
              d4 * __logf(d4) + d5 * __logf(d5) + d6 * __logf(d6) + d7 * __logf(d7);
    contrib = (float)deg * h;
  }
#pragma unroll
  for (int o = 32; o >= 1; o >>= 1) contrib += __shfl_xor(contrib, o, 64);
  __shared__ float red[4];
  int wave = threadIdx.x >> 6;
  if ((threadIdx.x & 63) == 0) red[wave] = contrib;
  __syncthreads();
  if (threadIdx.x == 0)
    atomicAdd(acc, (double)(red[0] + red[1] + red[2] + red[3]));
}

// ---- pull 2: acc -= sum_e dot(dvec[dst], logs[src]); last block finalizes ----
__global__ void pull_loss_kernel(const int* __restrict__ offsets,
                                 const int* __restrict__ sorted_src,
                                 const unsigned* __restrict__ logs,
                                 const float* __restrict__ dvec,
                                 double* __restrict__ acc,
                                 unsigned* __restrict__ done,
                                 float* __restrict__ out, int E, int N) {
  int gid = blockIdx.x * blockDim.x + threadIdx.x;
  int g = gid >> 1;
  int t = gid & 1;
  float dot = 0.f;
  if (g < N) {
    int beg = offsets[g], end = offsets[g + 1];
    float s0 = 0.f, s1 = 0.f, s2 = 0.f, s3 = 0.f, s4 = 0.f, s5 = 0.f, s6 = 0.f, s7 = 0.f;
    int woff = t << 2;
    int i = beg;
    for (; i + 8 <= end; i += 8) {
      int i0 = sorted_src[i],     i1 = sorted_src[i + 1];
      int i2 = sorted_src[i + 2], i3 = sorted_src[i + 3];
      int i4 = sorted_src[i + 4], i5 = sorted_src[i + 5];
      int i6 = sorted_src[i + 6], i7 = sorted_src[i + 7];
      uint4 w0 = *reinterpret_cast<const uint4*>(logs + ((size_t)i0 << 3) + woff);
      uint4 w1 = *reinterpret_cast<const uint4*>(logs + ((size_t)i1 << 3) + woff);
      uint4 w2 = *reinterpret_cast<const uint4*>(logs + ((size_t)i2 << 3) + woff);
      uint4 w3 = *reinterpret_cast<const uint4*>(logs + ((size_t)i3 << 3) + woff);
      uint4 w4 = *reinterpret_cast<const uint4*>(logs + ((size_t)i4 << 3) + woff);
      uint4 w5 = *reinterpret_cast<const uint4*>(logs + ((size_t)i5 << 3) + woff);
      uint4 w6 = *reinterpret_cast<const uint4*>(logs + ((size_t)i6 << 3) + woff);
      uint4 w7 = *reinterpret_cast<const uint4*>(logs + ((size_t)i7 << 3) + woff);
      s0 += bflo(w0.x) + bflo(w1.x) + bflo(w2.x) + bflo(w3.x) + bflo(w4.x) + bflo(w5.x) + bflo(w6.x) + bflo(w7.x);
      s1 += bfhi(w0.x) + bfhi(w1.x) + bfhi(w2.x) + bfhi(w3.x) + bfhi(w4.x) + bfhi(w5.x) + bfhi(w6.x) + bfhi(w7.x);
      s2 += bflo(w0.y) + bflo(w1.y) + bflo(w2.y) + bflo(w3.y) + bflo(w4.y) + bflo(w5.y) + bflo(w6.y) + bflo(w7.y);
      s3 += bfhi(w0.y) + bfhi(w1.y) + bfhi(w2.y) + bfhi(w3.y) + bfhi(w4.y) + bfhi(w5.y) + bfhi(w6.y) + bfhi(w7.y);
      s4 += bflo(w0.z) + bflo(w1.z) + bflo(w2.z) + bflo(w3.z) + bflo(w4.z) + bflo(w5.z) + bflo(w6.z) + bflo(w7.z);
      s5 += bfhi(w0.z) + bfhi(w1.z) + bfhi(w2.z) + bfhi(w3.z) + bfhi(w4.z) + bfhi(w5.z) + bfhi(w6.z) + bfhi(w7.z);
      s6 += bflo(w0.w) + bflo(w1.w) + bflo(w2.w) + bflo(w3.w) + bflo(w4.w) + bflo(w5.w) + bflo(w6.w) + bflo(w7.w);
      s7 += bfhi(w0.w) + bfhi(w1.w) + bfhi(w2.w) + bfhi(w3.w) + bfhi(w4.w) + bfhi(w5.w) + bfhi(w6.w) + bfhi(w7.w);
    }
    for (; i < end; i++) {
      int i0 = sorted_src[i];
      uint4 w0 = *reinterpret_cast<const uint4*>(logs + ((size_t)i0 << 3) + woff);
      s0 += bflo(w0.x); s1 += bfhi(w0.x);
      s2 += bflo(w0.y); s3 += bfhi(w0.y);
      s4 += bflo(w0.z); s5 += bfhi(w0.z);
      s6 += bflo(w0.w); s7 += bfhi(w0.w);
    }
    const float* dbase = dvec + ((size_t)g << 4) + (t << 3);
    float4 dd0 = *reinterpret_cast<const float4*>(dbase);
    float4 dd1 = *reinterpret_cast<const float4*>(dbase + 4);
    dot = dd0.x * s0 + dd0.y * s1 + dd0.z * s2 + dd0.w * s3 +
          dd1.x * s4 + dd1.y * s5 + dd1.z * s6 + dd1.w * s7;
  }
#pragma unroll
  for (int o = 32; o >= 1; o >>= 1) dot += __shfl_xor(dot, o, 64);
  __shared__ float red[4];
  int wave = threadIdx.x >> 6;
  if ((threadIdx.x & 63) == 0) red[wave] = dot;
  __syncthreads();
  if (threadIdx.x == 0) {
    atomicAdd(acc, -(double)(red[0] + red[1] + red[2] + red[3]));
    __threadfence();
    unsigned r = atomicAdd(done, 1u);
    if (r == gridDim.x - 1) {
      // atomic fetch: coherent read of the final sum (plain load could hit a
      // stale line in this XCD's non-coherent L2)
      double v = atomicAdd(acc, 0.0);
      out[0] = (float)(v / (double)E);
    }
  }
}

extern "C" void kernel_launch(void* const* d_in, const int* in_sizes, int n_in,
                              void* d_out, int out_size, void* d_ws, size_t ws_size,
                              hipStream_t stream) {
  const int* edge_index = (const int*)d_in[0];
  const float* aug_pred = (const float*)d_in[1];
  const int E = in_sizes[0] / 2;
  const int N = in_sizes[1] / NCLS;

  const int* srcv = edge_index;
  const int* dstv = edge_index + E;

  // 256B-aligned bump allocator over d_ws
  char* p = (char*)d_ws;
  auto alloc = [&](size_t bytes) {
    char* r = p;
    p += (bytes + 255) & ~(size_t)255;
    return r;
  };
  double* acc = (double*)alloc(8);       // + done counter shares this 256B slot
  unsigned* done = (unsigned*)((char*)acc + 8);
  int* bcnt = (int*)alloc(NB * 4);
  int* bbase = (int*)alloc((NB + 1) * 4);
  int* gcur = (int*)alloc(NB * 4);
  int* packed = (int*)alloc((size_t)E * 4);
  int* offsets = (int*)alloc((size_t)(N + 1) * 4);
  unsigned* augh = (unsigned*)alloc((size_t)N * NCLS * 2);
  unsigned* logs = (unsigned*)alloc((size_t)N * NCLS * 2);
  float* dvec = (float*)alloc((size_t)N * NCLS * 4);

  // zero acc + done + bcnt (contiguous prefix of the arena)
  size_t zero_bytes = (size_t)((char*)bbase - (char*)d_ws);
  hipMemsetAsync(d_ws, 0, zero_bytes, stream);

  int n2 = N * NCLS / 2;
  int cvtb = (n2 + 255) / 256;
  pre_kernel<<<PREB + cvtb, 256, 0, stream>>>(dstv, bcnt, E, (const float2*)aug_pred, augh, n2);
  bscan_kernel<<<1, 512, 0, stream>>>(bcnt, bbase, gcur, offsets, N, E);
  int tiles = (E + TILE - 1) / TILE;
  bin_kernel<<<tiles, 512, 0, stream>>>(srcv, dstv, gcur, packed, E);
  csr_sort_kernel<<<NB, 512, 0, stream>>>(bbase, packed, offsets, N);
  int pbl = ((size_t)N * 2 + 255) / 256;
  pull_node_kernel<<<pbl, 256, 0, stream>>>(offsets, packed, augh, logs, dvec, acc, N);
  pull_loss_kernel<<<pbl, 256, 0, stream>>>(offsets, packed, logs, dvec, acc, done,
                                            (float*)d_out, E, N);
}